// Round 9
// baseline (379.305 us; speedup 1.0000x reference)
//
#include <hip/hip_runtime.h>
#include <math.h>

#define NN 50000
#define EE 800000
#define GG 512
#define OUTC 100
#define NEG 0.2f
#define STRIDE 64
#define NPART 8
#define PRNG (NN / NPART)
#define PCHUNK 4096

typedef __attribute__((ext_vector_type(8))) short bf16x8;
typedef __attribute__((ext_vector_type(8))) short s16x8;
typedef __attribute__((ext_vector_type(8))) unsigned short us8;
typedef __attribute__((ext_vector_type(4))) float f32x4;

__device__ inline ushort f2bf(float v) {
  unsigned u = __float_as_uint(v);
  unsigned r = (u + 0x7fff + ((u >> 16) & 1)) >> 16;
  return (ushort)r;
}

// ---------------- dst-partitioned fixed-stride CSR scatter ----------------
__global__ __launch_bounds__(256) void k_scatter(const int* __restrict__ ei,
    int* __restrict__ cursor, ushort* __restrict__ srcs) {
  int part = blockIdx.x & (NPART - 1);
  int chunk = blockIdx.x >> 3;
  int lo = part * PRNG, hi = lo + PRNG;
  int base = chunk * PCHUNK;
  for (int i = threadIdx.x; i < PCHUNK; i += 256) {
    int e = base + i;
    if (e >= EE) break;
    int d = ei[EE + e];
    if (d < lo || d >= hi) continue;
    int s = ei[e];
    int pos = atomicAdd(&cursor[d], 1);
    if (pos < STRIDE) srcs[(d << 6) + pos] = (ushort)s;
  }
}

// ---------------- fused weight prep for all 3 layers ----------------
__global__ __launch_bounds__(256) void k_prep(
    const float* __restrict__ W0, const float* __restrict__ W1, const float* __restrict__ W2,
    const float* __restrict__ as0, const float* __restrict__ as1, const float* __restrict__ as2,
    const float* __restrict__ ad0, const float* __restrict__ ad1, const float* __restrict__ ad2,
    ushort* __restrict__ hi, ushort* __restrict__ lo) {
  int layer = blockIdx.y;
  const float* W  = (layer == 0) ? W0 : (layer == 1) ? W1 : W2;
  const float* av = (layer == 0) ? as0 : (layer == 1) ? as1 : as2;
  const float* dv = (layer == 0) ? ad0 : (layer == 1) ? ad1 : ad2;
  ushort* hiL = hi + (size_t)layer * 144 * 128;
  ushort* loL = lo + (size_t)layer * 144 * 128;
  int idx = blockIdx.x * 256 + threadIdx.x;
  if (blockIdx.x < 64) {
    float v = W[idx];
    ushort hb = f2bf(v);
    float hf = __uint_as_float(((unsigned)hb) << 16);
    hiL[idx] = hb;
    loL[idx] = f2bf(v - hf);
  } else {
    int j2 = idx - 64 * 256;
    int j = j2 >> 7, k = j2 & 127;
    int head = j & 3;
    const float* vec = (j < 4) ? &av[head * 32] : &dv[head * 32];
    float dot = 0.f;
#pragma unroll
    for (int c = 0; c < 32; c++) dot += W[(head * 32 + c) * 128 + k] * vec[c];
    ushort hb = f2bf(dot);
    float hf = __uint_as_float(((unsigned)hb) << 16);
    hiL[(128 + j) * 128 + k] = hb;
    loL[(128 + j) * 128 + k] = f2bf(dot - hf);
    hiL[(136 + j) * 128 + k] = 0;
    loL[(136 + j) * 128 + k] = 0;
  }
}

// ---------------- GEMM, LDS-free: A direct from global into MFMA A-layout ----------------
// wave w owns rows n0 + w*32 + mt*16 + r16; A-frag: m=r16, k=quad*8+j.
// 9 N-tiles: nt 0..7 = output channels, nt 8 = aug (attention logits).
__global__ __launch_bounds__(256) void k_gemm_mfma(const float* __restrict__ feat,
    const ushort* __restrict__ Whi, const ushort* __restrict__ Wlo,
    short* __restrict__ hq, float* __restrict__ scalef,
    float* __restrict__ asrcf, float* __restrict__ adstf) {
  int t = threadIdx.x;
  int wave = t >> 6, lane = t & 63;
  int quad = lane >> 4, r16 = lane & 15;
  int n0 = blockIdx.x * 128;

  f32x4 acc[2][9];
#pragma unroll
  for (int mt = 0; mt < 2; mt++)
#pragma unroll
    for (int nt = 0; nt < 9; nt++) acc[mt][nt] = (f32x4)0.f;

  for (int ks = 0; ks < 4; ks++) {
    bf16x8 bh[9], bl[9];
#pragma unroll
    for (int nt = 0; nt < 9; nt++) {
      int wrow = (nt < 8) ? (nt * 16 + r16) : (128 + r16);
      size_t wo = (size_t)wrow * 128 + ks * 32 + quad * 8;
      bh[nt] = *(const bf16x8*)&Whi[wo];
      bl[nt] = *(const bf16x8*)&Wlo[wo];
    }
#pragma unroll
    for (int mt = 0; mt < 2; mt++) {
      int row = n0 + wave * 32 + mt * 16 + r16;
      float4 va = make_float4(0.f, 0.f, 0.f, 0.f), vb = va;
      if (row < NN) {
        const float4* fp = (const float4*)&feat[(size_t)row * 128 + ks * 32 + quad * 8];
        va = fp[0]; vb = fp[1];
      }
      float vv[8] = {va.x, va.y, va.z, va.w, vb.x, vb.y, vb.z, vb.w};
      us8 hh, ll;
#pragma unroll
      for (int j = 0; j < 8; j++) {
        ushort hb = f2bf(vv[j]);
        float hf = __uint_as_float(((unsigned)hb) << 16);
        hh[j] = hb;
        ll[j] = (ushort)(__float_as_uint(vv[j] - hf) >> 16);  // truncated lo
      }
      bf16x8 ah = (bf16x8)hh, al = (bf16x8)ll;
#pragma unroll
      for (int nt = 0; nt < 9; nt++) {
        acc[mt][nt] = __builtin_amdgcn_mfma_f32_16x16x32_bf16(ah, bh[nt], acc[mt][nt], 0, 0, 0);
        acc[mt][nt] = __builtin_amdgcn_mfma_f32_16x16x32_bf16(al, bh[nt], acc[mt][nt], 0, 0, 0);
        acc[mt][nt] = __builtin_amdgcn_mfma_f32_16x16x32_bf16(ah, bl[nt], acc[mt][nt], 0, 0, 0);
      }
    }
  }

#pragma unroll
  for (int mt = 0; mt < 2; mt++) {
#pragma unroll
    for (int reg = 0; reg < 4; reg++) {
      float am = 0.f;
#pragma unroll
      for (int nt = 0; nt < 8; nt++) am = fmaxf(am, fabsf(acc[mt][nt][reg]));
#pragma unroll
      for (int off = 1; off < 16; off <<= 1) am = fmaxf(am, __shfl_xor(am, off));
      int node = n0 + wave * 32 + mt * 16 + quad * 4 + reg;
      if (node < NN) {
        float amc = fmaxf(am, 1e-20f);
        float rq = 32767.f / amc;
        if (r16 == 0) scalef[node] = amc * (1.f / 32767.f);
        if (r16 < 4) asrcf[node * 4 + r16] = acc[mt][8][reg];
        else if (r16 < 8) adstf[node * 4 + r16 - 4] = acc[mt][8][reg];
        short* dq = &hq[(size_t)node * 128 + r16];
#pragma unroll
        for (int nt = 0; nt < 8; nt++)
          dq[nt * 16] = (short)__float2int_rn(acc[mt][nt][reg] * rq);
      }
    }
  }
}

// ---------------- single-pass gather-aggregate (int16 rows, self-loop fused) ----------------
__global__ __launch_bounds__(256) void k_gather(const short* __restrict__ hq,
    const float* __restrict__ scalef,
    const float4* __restrict__ asrc, const float4* __restrict__ adst,
    const int* __restrict__ cursor, const ushort* __restrict__ srcs,
    const float* __restrict__ bias, float* __restrict__ outf) {
  __shared__ int s_src[4][4][16];
  __shared__ float s_w[4][4][72];
  __shared__ float s_e[4][4][72];

  int wave = threadIdx.x >> 6, lane = threadIdx.x & 63;
  int grp = lane >> 4;
  int gl = lane & 15;
  int node = blockIdx.x * 16 + wave * 4 + grp;

  int deg = 0, e0 = 0;
  float4 ad = make_float4(0.f, 0.f, 0.f, 0.f);
  if (node < NN) {
    deg = min(cursor[node], STRIDE);
    e0 = node << 6;
    ad = adst[node];
  }
  int c0 = gl << 3;
  int head = gl >> 2;

  float acc[8];
#pragma unroll
  for (int i = 0; i < 8; i++) acc[i] = 0.f;
  float wsum = 0.f;

  // self-loop contribution
  if (node < NN) {
    float4 a = asrc[node];
    float sc = scalef[node];
    float v, w0, w1, w2, w3;
    v = a.x + ad.x; v = v > 0.f ? v : NEG * v; w0 = expf(v);
    v = a.y + ad.y; v = v > 0.f ? v : NEG * v; w1 = expf(v);
    v = a.z + ad.z; v = v > 0.f ? v : NEG * v; w2 = expf(v);
    v = a.w + ad.w; v = v > 0.f ? v : NEG * v; w3 = expf(v);
    float wh = (head == 0) ? w0 : (head == 1) ? w1 : (head == 2) ? w2 : w3;
    wsum = wh;
    float ws = wh * sc;
    s16x8 qs = *(const s16x8*)&hq[(node << 7) + c0];
#pragma unroll
    for (int i = 0; i < 8; i++) acc[i] = ws * (float)qs[i];
  }

  int rounds = (deg + 15) >> 4;
  for (int r = 0; r < rounds; r++) {
    int base = r << 4;
    int j = base + gl;
    int sn = 0;
    float w0 = 0.f, w1 = 0.f, w2 = 0.f, w3 = 0.f, sc = 0.f;
    if (j < deg) {
      sn = srcs[e0 + j];
      float4 a = asrc[sn];
      sc = scalef[sn];
      float v;
      v = a.x + ad.x; v = v > 0.f ? v : NEG * v; w0 = expf(v);
      v = a.y + ad.y; v = v > 0.f ? v : NEG * v; w1 = expf(v);
      v = a.z + ad.z; v = v > 0.f ? v : NEG * v; w2 = expf(v);
      v = a.w + ad.w; v = v > 0.f ? v : NEG * v; w3 = expf(v);
    }
    s_src[wave][grp][gl] = sn << 7;
    float* wp = &s_w[wave][grp][gl << 2];
    wp[0] = w0 * sc; wp[1] = w1 * sc; wp[2] = w2 * sc; wp[3] = w3 * sc;
    float* ep = &s_e[wave][grp][gl << 2];
    ep[0] = w0; ep[1] = w1; ep[2] = w2; ep[3] = w3;
    __builtin_amdgcn_s_waitcnt(0);

    int cnt = min(16, deg - base);
    int cntp = (cnt + 7) & ~7;
    for (int k = 0; k < cntp; k += 8) {
      int rr[8]; float ww[8];
#pragma unroll
      for (int u = 0; u < 8; u++) {
        rr[u] = s_src[wave][grp][k + u];
        ww[u] = s_w[wave][grp][((k + u) << 2) | head];
        wsum += s_e[wave][grp][((k + u) << 2) | head];
      }
      s16x8 q0 = *(const s16x8*)&hq[rr[0] + c0];
      s16x8 q1 = *(const s16x8*)&hq[rr[1] + c0];
      s16x8 q2 = *(const s16x8*)&hq[rr[2] + c0];
      s16x8 q3 = *(const s16x8*)&hq[rr[3] + c0];
      s16x8 q4 = *(const s16x8*)&hq[rr[4] + c0];
      s16x8 q5 = *(const s16x8*)&hq[rr[5] + c0];
      s16x8 q6 = *(const s16x8*)&hq[rr[6] + c0];
      s16x8 q7 = *(const s16x8*)&hq[rr[7] + c0];
#pragma unroll
      for (int i = 0; i < 8; i++) acc[i] = fmaf(ww[0], (float)q0[i], acc[i]);
#pragma unroll
      for (int i = 0; i < 8; i++) acc[i] = fmaf(ww[1], (float)q1[i], acc[i]);
#pragma unroll
      for (int i = 0; i < 8; i++) acc[i] = fmaf(ww[2], (float)q2[i], acc[i]);
#pragma unroll
      for (int i = 0; i < 8; i++) acc[i] = fmaf(ww[3], (float)q3[i], acc[i]);
#pragma unroll
      for (int i = 0; i < 8; i++) acc[i] = fmaf(ww[4], (float)q4[i], acc[i]);
#pragma unroll
      for (int i = 0; i < 8; i++) acc[i] = fmaf(ww[5], (float)q5[i], acc[i]);
#pragma unroll
      for (int i = 0; i < 8; i++) acc[i] = fmaf(ww[6], (float)q6[i], acc[i]);
#pragma unroll
      for (int i = 0; i < 8; i++) acc[i] = fmaf(ww[7], (float)q7[i], acc[i]);
    }
  }

  if (node < NN) {
    float rcp = 1.f / (wsum + 1e-16f);
    float o[8];
#pragma unroll
    for (int i = 0; i < 8; i++) {
      float v = acc[i] * rcp + bias[c0 + i];
      o[i] = v > 0.f ? v : expm1f(v);
    }
    *(float4*)&outf[(size_t)node * 128 + c0] = make_float4(o[0], o[1], o[2], o[3]);
    *(float4*)&outf[(size_t)node * 128 + c0 + 4] = make_float4(o[4], o[5], o[6], o[7]);
  }
}

// ---------------- mean pool ----------------
__global__ __launch_bounds__(128) void k_pool(const float* __restrict__ feat,
    const int* __restrict__ batch, float* __restrict__ pooled, float* __restrict__ cnt) {
  int n0 = blockIdx.x * 32;
  int c = threadIdx.x;
  float acc = 0.f; int curg = -1;
  for (int i = 0; i < 32; i++) {
    int n = n0 + i;
    if (n >= NN) break;
    int g = batch[n];
    if (g != curg) {
      if (curg >= 0) atomicAdd(&pooled[curg * 128 + c], acc);
      acc = 0.f; curg = g;
    }
    acc += feat[n * 128 + c];
  }
  if (curg >= 0) atomicAdd(&pooled[curg * 128 + c], acc);
  if (threadIdx.x == 0) {
    float cc = 0.f; int cg = -1;
    for (int i = 0; i < 32; i++) {
      int n = n0 + i;
      if (n >= NN) break;
      int g = batch[n];
      if (g != cg) { if (cg >= 0) atomicAdd(&cnt[cg], cc); cc = 0.f; cg = g; }
      cc += 1.f;
    }
    if (cg >= 0) atomicAdd(&cnt[cg], cc);
  }
}

// ---------------- final FC ----------------
__global__ __launch_bounds__(128) void k_fc(const float* __restrict__ pooled,
    const float* __restrict__ cnt, const float* __restrict__ fcW,
    const float* __restrict__ fcb, float* __restrict__ out) {
  int g = blockIdx.x;
  __shared__ float p[128];
  int t = threadIdx.x;
  float inv = 1.0f / fmaxf(cnt[g], 1.0f);
  p[t] = pooled[g * 128 + t] * inv;
  __syncthreads();
  if (t < OUTC) {
    float acc = fcb[t];
    const float4* wr = (const float4*)&fcW[t * 128];
    const float4* pp = (const float4*)p;
#pragma unroll
    for (int i = 0; i < 32; i++) {
      float4 w = wr[i], pv = pp[i];
      acc = fmaf(w.x, pv.x, fmaf(w.y, pv.y, fmaf(w.z, pv.z, fmaf(w.w, pv.w, acc))));
    }
    out[g * OUTC + t] = acc;
  }
}

extern "C" void kernel_launch(void* const* d_in, const int* in_sizes, int n_in,
                              void* d_out, int out_size, void* d_ws, size_t ws_size,
                              hipStream_t stream) {
  const float* x    = (const float*)d_in[0];
  const int*   ei   = (const int*)d_in[1];
  const int*   batch= (const int*)d_in[2];
  const float* W1   = (const float*)d_in[3];
  const float* as1  = (const float*)d_in[4];
  const float* ad1  = (const float*)d_in[5];
  const float* b1   = (const float*)d_in[6];
  const float* W2   = (const float*)d_in[7];
  const float* as2  = (const float*)d_in[8];
  const float* ad2  = (const float*)d_in[9];
  const float* b2   = (const float*)d_in[10];
  const float* W3   = (const float*)d_in[11];
  const float* as3  = (const float*)d_in[12];
  const float* ad3  = (const float*)d_in[13];
  const float* b3   = (const float*)d_in[14];
  const float* fcW  = (const float*)d_in[15];
  const float* fcb  = (const float*)d_in[16];
  float* out = (float*)d_out;

  char* p = (char*)d_ws;
  auto alloc = [&](size_t bytes) { char* r = p; p += (bytes + 255) & ~(size_t)255; return r; };
  short* hq     = (short*)alloc((size_t)NN * 128 * 2);
  float* scalef = (float*)alloc((size_t)NN * 4);
  float* buf0   = (float*)alloc((size_t)NN * 128 * 4);
  float* asrc   = (float*)alloc((size_t)NN * 4 * 4);
  float* adst   = (float*)alloc((size_t)NN * 4 * 4);
  char*  zbase  = p;
  int*   cursor = (int*)alloc((size_t)NN * 4);
  float* pooled = (float*)alloc((size_t)GG * 128 * 4);
  float* cnt    = (float*)alloc((size_t)GG * 4);
  size_t zlen   = (size_t)(p - zbase);
  ushort* srcs  = (ushort*)alloc((size_t)NN * STRIDE * 2);
  ushort* whi   = (ushort*)alloc((size_t)3 * 144 * 128 * 2);
  ushort* wlo   = (ushort*)alloc((size_t)3 * 144 * 128 * 2);

  hipMemsetAsync(zbase, 0, zlen, stream);

  int nchunks = (EE + PCHUNK - 1) / PCHUNK;
  k_scatter<<<NPART * nchunks, 256, 0, stream>>>(ei, cursor, srcs);
  k_prep<<<dim3(68, 3), 256, 0, stream>>>(W1, W2, W3, as1, as2, as3, ad1, ad2, ad3, whi, wlo);

  const float* bs[3] = {b1, b2, b3};
  const float* fin = x;
  for (int l = 0; l < 3; l++) {
    k_gemm_mfma<<<(NN + 127) / 128, 256, 0, stream>>>(fin,
        whi + (size_t)l * 144 * 128, wlo + (size_t)l * 144 * 128,
        hq, scalef, asrc, adst);
    k_gather<<<(NN + 15) / 16, 256, 0, stream>>>(hq, scalef,
        (const float4*)asrc, (const float4*)adst,
        cursor, srcs, bs[l], buf0);
    fin = buf0;
  }
  k_pool<<<(NN + 31) / 32, 128, 0, stream>>>(buf0, batch, pooled, cnt);
  k_fc<<<GG, 128, 0, stream>>>(pooled, cnt, fcW, fcb, out);
}

// Round 10
// 367.105 us; speedup vs baseline: 1.0332x; 1.0332x over previous
//
#include <hip/hip_runtime.h>
#include <math.h>

#define NN 50000
#define EE 800000
#define GG 512
#define OUTC 100
#define NEG 0.2f
#define STRIDE 64
#define NPART 8
#define PRNG (NN / NPART)
#define PCHUNK 4096

typedef __attribute__((ext_vector_type(8))) short bf16x8;
typedef __attribute__((ext_vector_type(8))) short s16x8;
typedef __attribute__((ext_vector_type(8))) unsigned short us8;
typedef __attribute__((ext_vector_type(4))) float f32x4;

__device__ inline ushort f2bf(float v) {
  unsigned u = __float_as_uint(v);
  unsigned r = (u + 0x7fff + ((u >> 16) & 1)) >> 16;
  return (ushort)r;
}

// ---------------- dst-partitioned fixed-stride CSR scatter ----------------
__global__ __launch_bounds__(256) void k_scatter(const int* __restrict__ ei,
    int* __restrict__ cursor, ushort* __restrict__ srcs) {
  int part = blockIdx.x & (NPART - 1);
  int chunk = blockIdx.x >> 3;
  int lo = part * PRNG, hi = lo + PRNG;
  int base = chunk * PCHUNK;
  for (int i = threadIdx.x; i < PCHUNK; i += 256) {
    int e = base + i;
    if (e >= EE) break;
    int d = ei[EE + e];
    if (d < lo || d >= hi) continue;
    int s = ei[e];
    int pos = atomicAdd(&cursor[d], 1);
    if (pos < STRIDE) srcs[(d << 6) + pos] = (ushort)s;
  }
}

// ---------------- fused weight prep for all 3 layers ----------------
__global__ __launch_bounds__(256) void k_prep(
    const float* __restrict__ W0, const float* __restrict__ W1, const float* __restrict__ W2,
    const float* __restrict__ as0, const float* __restrict__ as1, const float* __restrict__ as2,
    const float* __restrict__ ad0, const float* __restrict__ ad1, const float* __restrict__ ad2,
    ushort* __restrict__ hi, ushort* __restrict__ lo) {
  int layer = blockIdx.y;
  const float* W  = (layer == 0) ? W0 : (layer == 1) ? W1 : W2;
  const float* av = (layer == 0) ? as0 : (layer == 1) ? as1 : as2;
  const float* dv = (layer == 0) ? ad0 : (layer == 1) ? ad1 : ad2;
  ushort* hiL = hi + (size_t)layer * 144 * 128;
  ushort* loL = lo + (size_t)layer * 144 * 128;
  int idx = blockIdx.x * 256 + threadIdx.x;
  if (blockIdx.x < 64) {
    float v = W[idx];
    ushort hb = f2bf(v);
    float hf = __uint_as_float(((unsigned)hb) << 16);
    hiL[idx] = hb;
    loL[idx] = f2bf(v - hf);
  } else {
    int j2 = idx - 64 * 256;
    int j = j2 >> 7, k = j2 & 127;
    int head = j & 3;
    const float* vec = (j < 4) ? &av[head * 32] : &dv[head * 32];
    float dot = 0.f;
#pragma unroll
    for (int c = 0; c < 32; c++) dot += W[(head * 32 + c) * 128 + k] * vec[c];
    ushort hb = f2bf(dot);
    float hf = __uint_as_float(((unsigned)hb) << 16);
    hiL[(128 + j) * 128 + k] = hb;
    loL[(128 + j) * 128 + k] = f2bf(dot - hf);
    hiL[(136 + j) * 128 + k] = 0;
    loL[(136 + j) * 128 + k] = 0;
  }
}

// ---------------- GEMM, LDS-free, short B live ranges ----------------
// A-frag direct from global (m=r16, k=quad*8+j); B reloaded per nt (L1-hot),
// ks fully unrolled so the compiler pipelines the A loads.
__global__ __launch_bounds__(256) void k_gemm_mfma(const float* __restrict__ feat,
    const ushort* __restrict__ Whi, const ushort* __restrict__ Wlo,
    short* __restrict__ hq, float* __restrict__ scalef,
    float* __restrict__ asrcf, float* __restrict__ adstf) {
  int t = threadIdx.x;
  int wave = t >> 6, lane = t & 63;
  int quad = lane >> 4, r16 = lane & 15;
  int n0 = blockIdx.x * 128;

  f32x4 acc[2][9];
#pragma unroll
  for (int mt = 0; mt < 2; mt++)
#pragma unroll
    for (int nt = 0; nt < 9; nt++) acc[mt][nt] = (f32x4)0.f;

#pragma unroll
  for (int ks = 0; ks < 4; ks++) {
    bf16x8 ah[2], al[2];
#pragma unroll
    for (int mt = 0; mt < 2; mt++) {
      int row = n0 + wave * 32 + mt * 16 + r16;
      float4 va = make_float4(0.f, 0.f, 0.f, 0.f), vb = va;
      if (row < NN) {
        const float4* fp = (const float4*)&feat[(size_t)row * 128 + ks * 32 + quad * 8];
        va = fp[0]; vb = fp[1];
      }
      float vv[8] = {va.x, va.y, va.z, va.w, vb.x, vb.y, vb.z, vb.w};
      us8 hh, ll;
#pragma unroll
      for (int j = 0; j < 8; j++) {
        ushort hb = f2bf(vv[j]);
        float hf = __uint_as_float(((unsigned)hb) << 16);
        hh[j] = hb;
        ll[j] = (ushort)(__float_as_uint(vv[j] - hf) >> 16);
      }
      ah[mt] = (bf16x8)hh;
      al[mt] = (bf16x8)ll;
    }
#pragma unroll
    for (int nt = 0; nt < 9; nt++) {
      int wrow = (nt < 8) ? (nt * 16 + r16) : (128 + r16);
      size_t wo = (size_t)wrow * 128 + ks * 32 + quad * 8;
      bf16x8 bh = *(const bf16x8*)&Whi[wo];
      bf16x8 bl = *(const bf16x8*)&Wlo[wo];
#pragma unroll
      for (int mt = 0; mt < 2; mt++) {
        acc[mt][nt] = __builtin_amdgcn_mfma_f32_16x16x32_bf16(ah[mt], bh, acc[mt][nt], 0, 0, 0);
        acc[mt][nt] = __builtin_amdgcn_mfma_f32_16x16x32_bf16(al[mt], bh, acc[mt][nt], 0, 0, 0);
        acc[mt][nt] = __builtin_amdgcn_mfma_f32_16x16x32_bf16(ah[mt], bl, acc[mt][nt], 0, 0, 0);
      }
    }
  }

#pragma unroll
  for (int mt = 0; mt < 2; mt++) {
#pragma unroll
    for (int reg = 0; reg < 4; reg++) {
      float am = 0.f;
#pragma unroll
      for (int nt = 0; nt < 8; nt++) am = fmaxf(am, fabsf(acc[mt][nt][reg]));
#pragma unroll
      for (int off = 1; off < 16; off <<= 1) am = fmaxf(am, __shfl_xor(am, off));
      int node = n0 + wave * 32 + mt * 16 + quad * 4 + reg;
      if (node < NN) {
        float amc = fmaxf(am, 1e-20f);
        float rq = 32767.f / amc;
        if (r16 == 0) scalef[node] = amc * (1.f / 32767.f);
        if (r16 < 4) asrcf[node * 4 + r16] = acc[mt][8][reg];
        else if (r16 < 8) adstf[node * 4 + r16 - 4] = acc[mt][8][reg];
        short* dq = &hq[(size_t)node * 128 + r16];
#pragma unroll
        for (int nt = 0; nt < 8; nt++)
          dq[nt * 16] = (short)__float2int_rn(acc[mt][nt][reg] * rq);
      }
    }
  }
}

// ---------------- single-pass gather-aggregate (round-8 proven: 4-deep, 32 VGPR) ----------------
__global__ __launch_bounds__(256) void k_gather(const short* __restrict__ hq,
    const float* __restrict__ scalef,
    const float4* __restrict__ asrc, const float4* __restrict__ adst,
    const int* __restrict__ cursor, const ushort* __restrict__ srcs,
    const float* __restrict__ bias, float* __restrict__ outf) {
  __shared__ int s_src[4][4][16];
  __shared__ float s_w[4][4][72];
  __shared__ float s_e[4][4][72];

  int wave = threadIdx.x >> 6, lane = threadIdx.x & 63;
  int grp = lane >> 4;
  int gl = lane & 15;
  int node = blockIdx.x * 16 + wave * 4 + grp;

  int deg = 0, e0 = 0;
  float4 ad = make_float4(0.f, 0.f, 0.f, 0.f);
  if (node < NN) {
    deg = min(cursor[node], STRIDE);
    e0 = node << 6;
    ad = adst[node];
  }
  int c0 = gl << 3;
  int head = gl >> 2;

  float acc[8];
#pragma unroll
  for (int i = 0; i < 8; i++) acc[i] = 0.f;
  float wsum = 0.f;

  // self-loop contribution
  if (node < NN) {
    float4 a = asrc[node];
    float sc = scalef[node];
    float v, w0, w1, w2, w3;
    v = a.x + ad.x; v = v > 0.f ? v : NEG * v; w0 = expf(v);
    v = a.y + ad.y; v = v > 0.f ? v : NEG * v; w1 = expf(v);
    v = a.z + ad.z; v = v > 0.f ? v : NEG * v; w2 = expf(v);
    v = a.w + ad.w; v = v > 0.f ? v : NEG * v; w3 = expf(v);
    float wh = (head == 0) ? w0 : (head == 1) ? w1 : (head == 2) ? w2 : w3;
    wsum = wh;
    float ws = wh * sc;
    s16x8 qs = *(const s16x8*)&hq[(node << 7) + c0];
#pragma unroll
    for (int i = 0; i < 8; i++) acc[i] = ws * (float)qs[i];
  }

  int rounds = (deg + 15) >> 4;
  for (int r = 0; r < rounds; r++) {
    int base = r << 4;
    int j = base + gl;
    int sn = 0;
    float w0 = 0.f, w1 = 0.f, w2 = 0.f, w3 = 0.f, sc = 0.f;
    if (j < deg) {
      sn = srcs[e0 + j];
      float4 a = asrc[sn];
      sc = scalef[sn];
      float v;
      v = a.x + ad.x; v = v > 0.f ? v : NEG * v; w0 = expf(v);
      v = a.y + ad.y; v = v > 0.f ? v : NEG * v; w1 = expf(v);
      v = a.z + ad.z; v = v > 0.f ? v : NEG * v; w2 = expf(v);
      v = a.w + ad.w; v = v > 0.f ? v : NEG * v; w3 = expf(v);
    }
    s_src[wave][grp][gl] = sn << 7;
    float* wp = &s_w[wave][grp][gl << 2];
    wp[0] = w0 * sc; wp[1] = w1 * sc; wp[2] = w2 * sc; wp[3] = w3 * sc;
    float* ep = &s_e[wave][grp][gl << 2];
    ep[0] = w0; ep[1] = w1; ep[2] = w2; ep[3] = w3;
    __builtin_amdgcn_s_waitcnt(0);

    int cnt = min(16, deg - base);
    int cntp = (cnt + 3) & ~3;
    for (int k = 0; k < cntp; k += 4) {
      int ra = s_src[wave][grp][k + 0];
      int rb = s_src[wave][grp][k + 1];
      int rc = s_src[wave][grp][k + 2];
      int rd = s_src[wave][grp][k + 3];
      float wa = s_w[wave][grp][((k + 0) << 2) | head];
      float wb = s_w[wave][grp][((k + 1) << 2) | head];
      float wc = s_w[wave][grp][((k + 2) << 2) | head];
      float wd = s_w[wave][grp][((k + 3) << 2) | head];
      wsum += s_e[wave][grp][((k + 0) << 2) | head]
            + s_e[wave][grp][((k + 1) << 2) | head]
            + s_e[wave][grp][((k + 2) << 2) | head]
            + s_e[wave][grp][((k + 3) << 2) | head];
      s16x8 qa = *(const s16x8*)&hq[ra + c0];
      s16x8 qb = *(const s16x8*)&hq[rb + c0];
      s16x8 qc = *(const s16x8*)&hq[rc + c0];
      s16x8 qd = *(const s16x8*)&hq[rd + c0];
#pragma unroll
      for (int i = 0; i < 8; i++) acc[i] = fmaf(wa, (float)qa[i], acc[i]);
#pragma unroll
      for (int i = 0; i < 8; i++) acc[i] = fmaf(wb, (float)qb[i], acc[i]);
#pragma unroll
      for (int i = 0; i < 8; i++) acc[i] = fmaf(wc, (float)qc[i], acc[i]);
#pragma unroll
      for (int i = 0; i < 8; i++) acc[i] = fmaf(wd, (float)qd[i], acc[i]);
    }
  }

  if (node < NN) {
    float rcp = 1.f / (wsum + 1e-16f);
    float o[8];
#pragma unroll
    for (int i = 0; i < 8; i++) {
      float v = acc[i] * rcp + bias[c0 + i];
      o[i] = v > 0.f ? v : expm1f(v);
    }
    *(float4*)&outf[(size_t)node * 128 + c0] = make_float4(o[0], o[1], o[2], o[3]);
    *(float4*)&outf[(size_t)node * 128 + c0 + 4] = make_float4(o[4], o[5], o[6], o[7]);
  }
}

// ---------------- mean pool ----------------
__global__ __launch_bounds__(128) void k_pool(const float* __restrict__ feat,
    const int* __restrict__ batch, float* __restrict__ pooled, float* __restrict__ cnt) {
  int n0 = blockIdx.x * 32;
  int c = threadIdx.x;
  float acc = 0.f; int curg = -1;
  for (int i = 0; i < 32; i++) {
    int n = n0 + i;
    if (n >= NN) break;
    int g = batch[n];
    if (g != curg) {
      if (curg >= 0) atomicAdd(&pooled[curg * 128 + c], acc);
      acc = 0.f; curg = g;
    }
    acc += feat[n * 128 + c];
  }
  if (curg >= 0) atomicAdd(&pooled[curg * 128 + c], acc);
  if (threadIdx.x == 0) {
    float cc = 0.f; int cg = -1;
    for (int i = 0; i < 32; i++) {
      int n = n0 + i;
      if (n >= NN) break;
      int g = batch[n];
      if (g != cg) { if (cg >= 0) atomicAdd(&cnt[cg], cc); cc = 0.f; cg = g; }
      cc += 1.f;
    }
    if (cg >= 0) atomicAdd(&cnt[cg], cc);
  }
}

// ---------------- final FC ----------------
__global__ __launch_bounds__(128) void k_fc(const float* __restrict__ pooled,
    const float* __restrict__ cnt, const float* __restrict__ fcW,
    const float* __restrict__ fcb, float* __restrict__ out) {
  int g = blockIdx.x;
  __shared__ float p[128];
  int t = threadIdx.x;
  float inv = 1.0f / fmaxf(cnt[g], 1.0f);
  p[t] = pooled[g * 128 + t] * inv;
  __syncthreads();
  if (t < OUTC) {
    float acc = fcb[t];
    const float4* wr = (const float4*)&fcW[t * 128];
    const float4* pp = (const float4*)p;
#pragma unroll
    for (int i = 0; i < 32; i++) {
      float4 w = wr[i], pv = pp[i];
      acc = fmaf(w.x, pv.x, fmaf(w.y, pv.y, fmaf(w.z, pv.z, fmaf(w.w, pv.w, acc))));
    }
    out[g * OUTC + t] = acc;
  }
}

extern "C" void kernel_launch(void* const* d_in, const int* in_sizes, int n_in,
                              void* d_out, int out_size, void* d_ws, size_t ws_size,
                              hipStream_t stream) {
  const float* x    = (const float*)d_in[0];
  const int*   ei   = (const int*)d_in[1];
  const int*   batch= (const int*)d_in[2];
  const float* W1   = (const float*)d_in[3];
  const float* as1  = (const float*)d_in[4];
  const float* ad1  = (const float*)d_in[5];
  const float* b1   = (const float*)d_in[6];
  const float* W2   = (const float*)d_in[7];
  const float* as2  = (const float*)d_in[8];
  const float* ad2  = (const float*)d_in[9];
  const float* b2   = (const float*)d_in[10];
  const float* W3   = (const float*)d_in[11];
  const float* as3  = (const float*)d_in[12];
  const float* ad3  = (const float*)d_in[13];
  const float* b3   = (const float*)d_in[14];
  const float* fcW  = (const float*)d_in[15];
  const float* fcb  = (const float*)d_in[16];
  float* out = (float*)d_out;

  char* p = (char*)d_ws;
  auto alloc = [&](size_t bytes) { char* r = p; p += (bytes + 255) & ~(size_t)255; return r; };
  short* hq     = (short*)alloc((size_t)NN * 128 * 2);
  float* scalef = (float*)alloc((size_t)NN * 4);
  float* buf0   = (float*)alloc((size_t)NN * 128 * 4);
  float* asrc   = (float*)alloc((size_t)NN * 4 * 4);
  float* adst   = (float*)alloc((size_t)NN * 4 * 4);
  char*  zbase  = p;
  int*   cursor = (int*)alloc((size_t)NN * 4);
  float* pooled = (float*)alloc((size_t)GG * 128 * 4);
  float* cnt    = (float*)alloc((size_t)GG * 4);
  size_t zlen   = (size_t)(p - zbase);
  ushort* srcs  = (ushort*)alloc((size_t)NN * STRIDE * 2);
  ushort* whi   = (ushort*)alloc((size_t)3 * 144 * 128 * 2);
  ushort* wlo   = (ushort*)alloc((size_t)3 * 144 * 128 * 2);

  hipMemsetAsync(zbase, 0, zlen, stream);

  int nchunks = (EE + PCHUNK - 1) / PCHUNK;
  k_scatter<<<NPART * nchunks, 256, 0, stream>>>(ei, cursor, srcs);
  k_prep<<<dim3(68, 3), 256, 0, stream>>>(W1, W2, W3, as1, as2, as3, ad1, ad2, ad3, whi, wlo);

  const float* bs[3] = {b1, b2, b3};
  const float* fin = x;
  for (int l = 0; l < 3; l++) {
    k_gemm_mfma<<<(NN + 127) / 128, 256, 0, stream>>>(fin,
        whi + (size_t)l * 144 * 128, wlo + (size_t)l * 144 * 128,
        hq, scalef, asrc, adst);
    k_gather<<<(NN + 15) / 16, 256, 0, stream>>>(hq, scalef,
        (const float4*)asrc, (const float4*)adst,
        cursor, srcs, bs[l], buf0);
    fin = buf0;
  }
  k_pool<<<(NN + 31) / 32, 128, 0, stream>>>(buf0, batch, pooled, cnt);
  k_fc<<<GG, 128, 0, stream>>>(pooled, cnt, fcW, fcb, out);
}

// Round 11
// 359.609 us; speedup vs baseline: 1.0548x; 1.0208x over previous
//
#include <hip/hip_runtime.h>
#include <math.h>

#define NN 50000
#define EE 800000
#define GG 512
#define OUTC 100
#define NEG 0.2f
#define STRIDE 64
#define NPART 8
#define PRNG (NN / NPART)
#define PCHUNK 4096
#define SCAT_BLOCKS (NPART * 196)   // 196 chunks of 4096 cover 800k edges

typedef __attribute__((ext_vector_type(8))) short bf16x8;
typedef __attribute__((ext_vector_type(8))) short s16x8;
typedef __attribute__((ext_vector_type(8))) unsigned short us8;
typedef __attribute__((ext_vector_type(4))) float f32x4;

__device__ inline ushort f2bf(float v) {
  unsigned u = __float_as_uint(v);
  unsigned r = (u + 0x7fff + ((u >> 16) & 1)) >> 16;
  return (ushort)r;
}

// ---------------- scatter (dst-partitioned) + weight prep, one dispatch ----------------
__global__ __launch_bounds__(256) void k_scatter_prep(const int* __restrict__ ei,
    int* __restrict__ cursor, ushort* __restrict__ srcs,
    const float* __restrict__ W0, const float* __restrict__ W1, const float* __restrict__ W2,
    const float* __restrict__ as0, const float* __restrict__ as1, const float* __restrict__ as2,
    const float* __restrict__ ad0, const float* __restrict__ ad1, const float* __restrict__ ad2,
    ushort* __restrict__ hi, ushort* __restrict__ lo) {
  if (blockIdx.x < SCAT_BLOCKS) {
    int part = blockIdx.x & (NPART - 1);
    int chunk = blockIdx.x >> 3;
    int plo = part * PRNG, phi = plo + PRNG;
    int base = chunk * PCHUNK;
    for (int i = threadIdx.x; i < PCHUNK; i += 256) {
      int e = base + i;
      if (e >= EE) break;
      int d = ei[EE + e];
      if (d < plo || d >= phi) continue;
      int s = ei[e];
      int pos = atomicAdd(&cursor[d], 1);
      if (pos < STRIDE) srcs[(d << 6) + pos] = (ushort)s;
    }
  } else {
    int pb = blockIdx.x - SCAT_BLOCKS;          // 0..203
    int layer = pb / 68, bx = pb % 68;
    const float* W  = (layer == 0) ? W0 : (layer == 1) ? W1 : W2;
    const float* av = (layer == 0) ? as0 : (layer == 1) ? as1 : as2;
    const float* dv = (layer == 0) ? ad0 : (layer == 1) ? ad1 : ad2;
    ushort* hiL = hi + (size_t)layer * 144 * 128;
    ushort* loL = lo + (size_t)layer * 144 * 128;
    int idx = bx * 256 + threadIdx.x;
    if (bx < 64) {
      float v = W[idx];
      ushort hb = f2bf(v);
      float hf = __uint_as_float(((unsigned)hb) << 16);
      hiL[idx] = hb;
      loL[idx] = f2bf(v - hf);
    } else {
      int j2 = idx - 64 * 256;
      int j = j2 >> 7, k = j2 & 127;
      int head = j & 3;
      const float* vec = (j < 4) ? &av[head * 32] : &dv[head * 32];
      float dot = 0.f;
#pragma unroll
      for (int c = 0; c < 32; c++) dot += W[(head * 32 + c) * 128 + k] * vec[c];
      ushort hb = f2bf(dot);
      float hf = __uint_as_float(((unsigned)hb) << 16);
      hiL[(128 + j) * 128 + k] = hb;
      loL[(128 + j) * 128 + k] = f2bf(dot - hf);
      hiL[(136 + j) * 128 + k] = 0;
      loL[(136 + j) * 128 + k] = 0;
    }
  }
}

// ---------------- GEMM core (templated tail guard) ----------------
template <bool TAIL>
__device__ __forceinline__ void gemm_core(const float* __restrict__ feat,
    const ushort* __restrict__ Whi, const ushort* __restrict__ Wlo,
    short* __restrict__ hq, float* __restrict__ scalef,
    float* __restrict__ asrcf, float* __restrict__ adstf, int n0, int t) {
  int wave = t >> 6, lane = t & 63;
  int quad = lane >> 4, r16 = lane & 15;

  f32x4 acc[2][9];
#pragma unroll
  for (int mt = 0; mt < 2; mt++)
#pragma unroll
    for (int nt = 0; nt < 9; nt++) acc[mt][nt] = (f32x4)0.f;

#pragma unroll
  for (int ks = 0; ks < 4; ks++) {
    bf16x8 ah[2], al[2];
#pragma unroll
    for (int mt = 0; mt < 2; mt++) {
      int row = n0 + wave * 32 + mt * 16 + r16;
      float4 va, vb;
      if (TAIL && row >= NN) {
        va = make_float4(0.f, 0.f, 0.f, 0.f); vb = va;
      } else {
        const float4* fp = (const float4*)&feat[(size_t)row * 128 + ks * 32 + quad * 8];
        va = fp[0]; vb = fp[1];
      }
      float vv[8] = {va.x, va.y, va.z, va.w, vb.x, vb.y, vb.z, vb.w};
      us8 hh, ll;
#pragma unroll
      for (int j = 0; j < 8; j++) {
        ushort hb = f2bf(vv[j]);
        float hf = __uint_as_float(((unsigned)hb) << 16);
        hh[j] = hb;
        ll[j] = (ushort)(__float_as_uint(vv[j] - hf) >> 16);
      }
      ah[mt] = (bf16x8)hh;
      al[mt] = (bf16x8)ll;
    }
#pragma unroll
    for (int nt = 0; nt < 9; nt++) {
      int wrow = (nt < 8) ? (nt * 16 + r16) : (128 + r16);
      size_t wo = (size_t)wrow * 128 + ks * 32 + quad * 8;
      bf16x8 bh = *(const bf16x8*)&Whi[wo];
      bf16x8 bl = *(const bf16x8*)&Wlo[wo];
#pragma unroll
      for (int mt = 0; mt < 2; mt++) {
        acc[mt][nt] = __builtin_amdgcn_mfma_f32_16x16x32_bf16(ah[mt], bh, acc[mt][nt], 0, 0, 0);
        acc[mt][nt] = __builtin_amdgcn_mfma_f32_16x16x32_bf16(al[mt], bh, acc[mt][nt], 0, 0, 0);
        acc[mt][nt] = __builtin_amdgcn_mfma_f32_16x16x32_bf16(ah[mt], bl, acc[mt][nt], 0, 0, 0);
      }
    }
  }

#pragma unroll
  for (int mt = 0; mt < 2; mt++) {
#pragma unroll
    for (int reg = 0; reg < 4; reg++) {
      float am = 0.f;
#pragma unroll
      for (int nt = 0; nt < 8; nt++) am = fmaxf(am, fabsf(acc[mt][nt][reg]));
#pragma unroll
      for (int off = 1; off < 16; off <<= 1) am = fmaxf(am, __shfl_xor(am, off));
      int node = n0 + wave * 32 + mt * 16 + quad * 4 + reg;
      if (!TAIL || node < NN) {
        float amc = fmaxf(am, 1e-20f);
        float rq = 32767.f / amc;
        if (r16 == 0) scalef[node] = amc * (1.f / 32767.f);
        if (r16 < 4) asrcf[node * 4 + r16] = acc[mt][8][reg];
        else if (r16 < 8) adstf[node * 4 + r16 - 4] = acc[mt][8][reg];
        short* dq = &hq[(size_t)node * 128 + r16];
#pragma unroll
        for (int nt = 0; nt < 8; nt++)
          dq[nt * 16] = (short)__float2int_rn(acc[mt][nt][reg] * rq);
      }
    }
  }
}

__global__ __launch_bounds__(256) void k_gemm_mfma(const float* __restrict__ feat,
    const ushort* __restrict__ Whi, const ushort* __restrict__ Wlo,
    short* __restrict__ hq, float* __restrict__ scalef,
    float* __restrict__ asrcf, float* __restrict__ adstf) {
  int n0 = blockIdx.x * 128;
  if (n0 + 128 <= NN)
    gemm_core<false>(feat, Whi, Wlo, hq, scalef, asrcf, adstf, n0, threadIdx.x);
  else
    gemm_core<true>(feat, Whi, Wlo, hq, scalef, asrcf, adstf, n0, threadIdx.x);
}

// ---------------- single-pass gather-aggregate (4-deep, 32 VGPR) ----------------
__global__ __launch_bounds__(256) void k_gather(const short* __restrict__ hq,
    const float* __restrict__ scalef,
    const float4* __restrict__ asrc, const float4* __restrict__ adst,
    const int* __restrict__ cursor, const ushort* __restrict__ srcs,
    const float* __restrict__ bias, float* __restrict__ outf) {
  __shared__ int s_src[4][4][16];
  __shared__ float s_w[4][4][72];
  __shared__ float s_e[4][4][72];

  int wave = threadIdx.x >> 6, lane = threadIdx.x & 63;
  int grp = lane >> 4;
  int gl = lane & 15;
  int node = blockIdx.x * 16 + wave * 4 + grp;

  int deg = 0, e0 = 0;
  float4 ad = make_float4(0.f, 0.f, 0.f, 0.f);
  if (node < NN) {
    deg = min(cursor[node], STRIDE);
    e0 = node << 6;
    ad = adst[node];
  }
  int c0 = gl << 3;
  int head = gl >> 2;

  float acc[8];
#pragma unroll
  for (int i = 0; i < 8; i++) acc[i] = 0.f;
  float wsum = 0.f;

  // self-loop contribution
  if (node < NN) {
    float4 a = asrc[node];
    float sc = scalef[node];
    float v, w0, w1, w2, w3;
    v = a.x + ad.x; v = v > 0.f ? v : NEG * v; w0 = expf(v);
    v = a.y + ad.y; v = v > 0.f ? v : NEG * v; w1 = expf(v);
    v = a.z + ad.z; v = v > 0.f ? v : NEG * v; w2 = expf(v);
    v = a.w + ad.w; v = v > 0.f ? v : NEG * v; w3 = expf(v);
    float wh = (head == 0) ? w0 : (head == 1) ? w1 : (head == 2) ? w2 : w3;
    wsum = wh;
    float ws = wh * sc;
    s16x8 qs = *(const s16x8*)&hq[(node << 7) + c0];
#pragma unroll
    for (int i = 0; i < 8; i++) acc[i] = ws * (float)qs[i];
  }

  int rounds = (deg + 15) >> 4;
  for (int r = 0; r < rounds; r++) {
    int base = r << 4;
    int j = base + gl;
    int sn = 0;
    float w0 = 0.f, w1 = 0.f, w2 = 0.f, w3 = 0.f, sc = 0.f;
    if (j < deg) {
      sn = srcs[e0 + j];
      float4 a = asrc[sn];
      sc = scalef[sn];
      float v;
      v = a.x + ad.x; v = v > 0.f ? v : NEG * v; w0 = expf(v);
      v = a.y + ad.y; v = v > 0.f ? v : NEG * v; w1 = expf(v);
      v = a.z + ad.z; v = v > 0.f ? v : NEG * v; w2 = expf(v);
      v = a.w + ad.w; v = v > 0.f ? v : NEG * v; w3 = expf(v);
    }
    s_src[wave][grp][gl] = sn << 7;
    float* wp = &s_w[wave][grp][gl << 2];
    wp[0] = w0 * sc; wp[1] = w1 * sc; wp[2] = w2 * sc; wp[3] = w3 * sc;
    float* ep = &s_e[wave][grp][gl << 2];
    ep[0] = w0; ep[1] = w1; ep[2] = w2; ep[3] = w3;
    // compiler inserts the minimal lgkm waits for LDS RAW

    int cnt = min(16, deg - base);
    int cntp = (cnt + 3) & ~3;
    for (int k = 0; k < cntp; k += 4) {
      int ra = s_src[wave][grp][k + 0];
      int rb = s_src[wave][grp][k + 1];
      int rc = s_src[wave][grp][k + 2];
      int rd = s_src[wave][grp][k + 3];
      float wa = s_w[wave][grp][((k + 0) << 2) | head];
      float wb = s_w[wave][grp][((k + 1) << 2) | head];
      float wc = s_w[wave][grp][((k + 2) << 2) | head];
      float wd = s_w[wave][grp][((k + 3) << 2) | head];
      wsum += s_e[wave][grp][((k + 0) << 2) | head]
            + s_e[wave][grp][((k + 1) << 2) | head]
            + s_e[wave][grp][((k + 2) << 2) | head]
            + s_e[wave][grp][((k + 3) << 2) | head];
      s16x8 qa = *(const s16x8*)&hq[ra + c0];
      s16x8 qb = *(const s16x8*)&hq[rb + c0];
      s16x8 qc = *(const s16x8*)&hq[rc + c0];
      s16x8 qd = *(const s16x8*)&hq[rd + c0];
#pragma unroll
      for (int i = 0; i < 8; i++) acc[i] = fmaf(wa, (float)qa[i], acc[i]);
#pragma unroll
      for (int i = 0; i < 8; i++) acc[i] = fmaf(wb, (float)qb[i], acc[i]);
#pragma unroll
      for (int i = 0; i < 8; i++) acc[i] = fmaf(wc, (float)qc[i], acc[i]);
#pragma unroll
      for (int i = 0; i < 8; i++) acc[i] = fmaf(wd, (float)qd[i], acc[i]);
    }
  }

  if (node < NN) {
    float rcp = 1.f / (wsum + 1e-16f);
    float o[8];
#pragma unroll
    for (int i = 0; i < 8; i++) {
      float v = acc[i] * rcp + bias[c0 + i];
      o[i] = v > 0.f ? v : expm1f(v);
    }
    *(float4*)&outf[(size_t)node * 128 + c0] = make_float4(o[0], o[1], o[2], o[3]);
    *(float4*)&outf[(size_t)node * 128 + c0 + 4] = make_float4(o[4], o[5], o[6], o[7]);
  }
}

// ---------------- mean pool ----------------
__global__ __launch_bounds__(128) void k_pool(const float* __restrict__ feat,
    const int* __restrict__ batch, float* __restrict__ pooled, float* __restrict__ cnt) {
  int n0 = blockIdx.x * 32;
  int c = threadIdx.x;
  float acc = 0.f; int curg = -1;
  for (int i = 0; i < 32; i++) {
    int n = n0 + i;
    if (n >= NN) break;
    int g = batch[n];
    if (g != curg) {
      if (curg >= 0) atomicAdd(&pooled[curg * 128 + c], acc);
      acc = 0.f; curg = g;
    }
    acc += feat[n * 128 + c];
  }
  if (curg >= 0) atomicAdd(&pooled[curg * 128 + c], acc);
  if (threadIdx.x == 0) {
    float cc = 0.f; int cg = -1;
    for (int i = 0; i < 32; i++) {
      int n = n0 + i;
      if (n >= NN) break;
      int g = batch[n];
      if (g != cg) { if (cg >= 0) atomicAdd(&cnt[cg], cc); cc = 0.f; cg = g; }
      cc += 1.f;
    }
    if (cg >= 0) atomicAdd(&cnt[cg], cc);
  }
}

// ---------------- final FC ----------------
__global__ __launch_bounds__(128) void k_fc(const float* __restrict__ pooled,
    const float* __restrict__ cnt, const float* __restrict__ fcW,
    const float* __restrict__ fcb, float* __restrict__ out) {
  int g = blockIdx.x;
  __shared__ float p[128];
  int t = threadIdx.x;
  float inv = 1.0f / fmaxf(cnt[g], 1.0f);
  p[t] = pooled[g * 128 + t] * inv;
  __syncthreads();
  if (t < OUTC) {
    float acc = fcb[t];
    const float4* wr = (const float4*)&fcW[t * 128];
    const float4* pp = (const float4*)p;
#pragma unroll
    for (int i = 0; i < 32; i++) {
      float4 w = wr[i], pv = pp[i];
      acc = fmaf(w.x, pv.x, fmaf(w.y, pv.y, fmaf(w.z, pv.z, fmaf(w.w, pv.w, acc))));
    }
    out[g * OUTC + t] = acc;
  }
}

extern "C" void kernel_launch(void* const* d_in, const int* in_sizes, int n_in,
                              void* d_out, int out_size, void* d_ws, size_t ws_size,
                              hipStream_t stream) {
  const float* x    = (const float*)d_in[0];
  const int*   ei   = (const int*)d_in[1];
  const int*   batch= (const int*)d_in[2];
  const float* W1   = (const float*)d_in[3];
  const float* as1  = (const float*)d_in[4];
  const float* ad1  = (const float*)d_in[5];
  const float* b1   = (const float*)d_in[6];
  const float* W2   = (const float*)d_in[7];
  const float* as2  = (const float*)d_in[8];
  const float* ad2  = (const float*)d_in[9];
  const float* b2   = (const float*)d_in[10];
  const float* W3   = (const float*)d_in[11];
  const float* as3  = (const float*)d_in[12];
  const float* ad3  = (const float*)d_in[13];
  const float* b3   = (const float*)d_in[14];
  const float* fcW  = (const float*)d_in[15];
  const float* fcb  = (const float*)d_in[16];
  float* out = (float*)d_out;

  char* p = (char*)d_ws;
  auto alloc = [&](size_t bytes) { char* r = p; p += (bytes + 255) & ~(size_t)255; return r; };
  short* hq     = (short*)alloc((size_t)NN * 128 * 2);
  float* scalef = (float*)alloc((size_t)NN * 4);
  float* buf0   = (float*)alloc((size_t)NN * 128 * 4);
  float* asrc   = (float*)alloc((size_t)NN * 4 * 4);
  float* adst   = (float*)alloc((size_t)NN * 4 * 4);
  char*  zbase  = p;
  int*   cursor = (int*)alloc((size_t)NN * 4);
  float* pooled = (float*)alloc((size_t)GG * 128 * 4);
  float* cnt    = (float*)alloc((size_t)GG * 4);
  size_t zlen   = (size_t)(p - zbase);
  ushort* srcs  = (ushort*)alloc((size_t)NN * STRIDE * 2);
  ushort* whi   = (ushort*)alloc((size_t)3 * 144 * 128 * 2);
  ushort* wlo   = (ushort*)alloc((size_t)3 * 144 * 128 * 2);

  hipMemsetAsync(zbase, 0, zlen, stream);

  k_scatter_prep<<<SCAT_BLOCKS + 204, 256, 0, stream>>>(ei, cursor, srcs,
      W1, W2, W3, as1, as2, as3, ad1, ad2, ad3, whi, wlo);

  const float* bs[3] = {b1, b2, b3};
  const float* fin = x;
  for (int l = 0; l < 3; l++) {
    k_gemm_mfma<<<(NN + 127) / 128, 256, 0, stream>>>(fin,
        whi + (size_t)l * 144 * 128, wlo + (size_t)l * 144 * 128,
        hq, scalef, asrc, adst);
    k_gather<<<(NN + 15) / 16, 256, 0, stream>>>(hq, scalef,
        (const float4*)asrc, (const float4*)adst,
        cursor, srcs, bs[l], buf0);
    fin = buf0;
  }
  k_pool<<<(NN + 31) / 32, 128, 0, stream>>>(buf0, batch, pooled, cnt);
  k_fc<<<GG, 128, 0, stream>>>(pooled, cnt, fcW, fcb, out);
}